// Round 2
// baseline (718.129 us; speedup 1.0000x reference)
//
#include <hip/hip_runtime.h>
#include <cstdint>
#include <cstddef>

// RNN-T joint. B=4,T=256,U=64, ENC=DEC=640, INNER=512, VOCAB=2048.
// out fp32 (4,256,64,2048) = 536 MB.
//
// Structure (round 2): H is never materialized in global memory.
//   cast_all:  all four fp32->bf16 casts in one launch
//   gemm_pipe: Pe = enc @ W1e^T, Pd = dec @ W1d^T (fp32 out)  [round-1 verified]
//   joint_fused: per 128-row m-panel: H-tile = tanh(Pe+Pd+b1) -> LDS (128 KiB),
//                then 8 n-tiles of 256 cols vs W2 (BK=32 double-buffered LDS).

typedef __attribute__((ext_vector_type(8))) short   short8;   // 8 bf16
typedef __attribute__((ext_vector_type(4))) float   floatx4;  // MFMA acc

__device__ __forceinline__ short f2bf(float f) {
  union { float f; unsigned u; } v; v.f = f;
  unsigned r = (v.u + 0x7fffu + ((v.u >> 16) & 1u)) >> 16;  // RNE
  return (short)(unsigned short)r;
}

// async global->LDS, 16B per lane (global_load_lds_dwordx4)
__device__ __forceinline__ void async16(const void* g, void* l) {
  __builtin_amdgcn_global_load_lds(
      (const __attribute__((address_space(1))) unsigned int*)g,
      (__attribute__((address_space(3))) unsigned int*)l,
      16, 0, 0);
}

// ---------------------------------------------------------------------------
// All four fp32->bf16 casts in one kernel. 8 elems/thread.
// n8: enc 81920 | dec 20480 | W1 81920 | W2 131072 ; total 315392 = 1232*256.
// ---------------------------------------------------------------------------
__global__ __launch_bounds__(256)
void cast_all(const float* __restrict__ enc, const float* __restrict__ dec,
              const float* __restrict__ W1,  const float* __restrict__ W2,
              short* __restrict__ encb, short* __restrict__ decb,
              short* __restrict__ W1b,  short* __restrict__ W2b)
{
  const int i = blockIdx.x * 256 + threadIdx.x;
  const float* in; short* out; int j;
  if (i < 81920)       { in = enc; out = encb; j = i; }
  else if (i < 102400) { in = dec; out = decb; j = i - 81920; }
  else if (i < 184320) { in = W1;  out = W1b;  j = i - 102400; }
  else                 { in = W2;  out = W2b;  j = i - 184320; }
  const float4* p = (const float4*)in + 2 * (size_t)j;
  const float4 a = p[0], b = p[1];
  short8 o;
  o[0] = f2bf(a.x); o[1] = f2bf(a.y); o[2] = f2bf(a.z); o[3] = f2bf(a.w);
  o[4] = f2bf(b.x); o[5] = f2bf(b.y); o[6] = f2bf(b.z); o[7] = f2bf(b.w);
  ((short8*)out)[j] = o;
}

// ---------------------------------------------------------------------------
// Pipelined bf16 GEMM (round-1 verified) — used for the two projections only.
// C[m][n] = sum_k A[m][k]*B[n][k]. BM=128, BN=256, BK=64, 8 waves, 3 LDS bufs,
// lookahead-2 counted vmcnt, T2 swizzle, T5 setprio, m204 XCD swizzle.
// ---------------------------------------------------------------------------
#define BUFB 49152

__global__ __launch_bounds__(512, 2)
void gemm_pipe(const short* __restrict__ A, int lda,
               const short* __restrict__ B, int ldb, int bcol,
               float* __restrict__ Cout, int ldc,
               const float* __restrict__ bias, int K, int nbx_sh)
{
  extern __shared__ char lds[];
  const int tid  = threadIdx.x;
  const int lane = tid & 63;
  const int w    = tid >> 6;
  const int wm   = (w >> 2) << 6;
  const int wn   = (w & 3) << 6;

  const int nwg = gridDim.x;
  const int qq = nwg >> 3, rr = nwg & 7;
  const int xcd = blockIdx.x & 7, idx = blockIdx.x >> 3;
  const int wg = (xcd < rr ? xcd * (qq + 1) : rr * (qq + 1) + (xcd - rr) * qq) + idx;
  const int nbx_mask = (1 << nbx_sh) - 1;
  const int m_base = (wg >> nbx_sh) << 7;
  const int n_base = (wg & nbx_mask) << 8;

  const int srow = tid >> 3;
  const int sblk = (tid & 7) ^ (srow & 7);
  const short* Asrc = A + (size_t)(m_base + srow) * lda + (sblk << 3);
  const short* Bsrc = B + (size_t)(n_base + srow) * ldb + bcol + (sblk << 3);
  const size_t a64 = (size_t)64 * lda;
  const size_t b64 = (size_t)64 * ldb;
  char* const ldst = lds + tid * 16;

  const int arow = lane & 15;
  const int q4   = lane >> 4;
  const int s7   = arow & 7;
  const int koff0 = ((q4)     ^ s7) << 4;
  const int koff1 = ((q4 + 4) ^ s7) << 4;
  const size_t aoff = (size_t)(wm + arow) * 128;
  const size_t boff = 16384 + (size_t)(wn + arow) * 128;

  floatx4 acc[4][4];
#pragma unroll
  for (int i = 0; i < 4; i++)
#pragma unroll
    for (int j = 0; j < 4; j++) acc[i][j] = (floatx4)0.0f;

  const int NT = K >> 6;

#pragma unroll
  for (int t = 0; t < 2; ++t) {
    const int kb = t << 6;
    char* dA = ldst + t * BUFB;
    char* dB = dA + 16384;
    async16(Asrc + kb,             dA);
    async16(Asrc + kb + a64,       dA + 8192);
    async16(Bsrc + kb,             dB);
    async16(Bsrc + kb + b64,       dB + 8192);
    async16(Bsrc + kb + 2 * b64,   dB + 16384);
    async16(Bsrc + kb + 3 * b64,   dB + 24576);
  }

  int r = 0;
  for (int kt = 0; kt < NT; ++kt) {
    if (kt + 1 < NT) asm volatile("s_waitcnt vmcnt(6)" ::: "memory");
    else             asm volatile("s_waitcnt vmcnt(0)" ::: "memory");
    __builtin_amdgcn_s_barrier();
    asm volatile("" ::: "memory");

    const char* Ab = lds + r * BUFB + aoff;
    const char* Bb = lds + r * BUFB + boff;
    const int r2 = (r >= 1) ? r - 1 : 2;
    char* dA = ldst + r2 * BUFB;
    char* dB = dA + 16384;
    const int  kb2 = (kt + 2) << 6;
    const bool do_stage = (kt + 2 < NT);

    short8 af[4], bf[4];

#pragma unroll
    for (int i = 0; i < 4; i++) af[i] = *(const short8*)(Ab + i * 2048 + koff0);
#pragma unroll
    for (int j = 0; j < 4; j++) bf[j] = *(const short8*)(Bb + j * 2048 + koff0);
    if (do_stage) {
      async16(Asrc + kb2,           dA);
      async16(Asrc + kb2 + a64,     dA + 8192);
      async16(Bsrc + kb2,           dB);
    }
    __builtin_amdgcn_s_barrier();
    asm volatile("s_waitcnt lgkmcnt(0)" ::: "memory");
    __builtin_amdgcn_s_setprio(1);
#pragma unroll
    for (int i = 0; i < 4; i++)
#pragma unroll
      for (int j = 0; j < 4; j++)
        acc[i][j] = __builtin_amdgcn_mfma_f32_16x16x32_bf16(af[i], bf[j], acc[i][j], 0, 0, 0);
    __builtin_amdgcn_s_setprio(0);

#pragma unroll
    for (int i = 0; i < 4; i++) af[i] = *(const short8*)(Ab + i * 2048 + koff1);
#pragma unroll
    for (int j = 0; j < 4; j++) bf[j] = *(const short8*)(Bb + j * 2048 + koff1);
    if (do_stage) {
      async16(Bsrc + kb2 + b64,     dB + 8192);
      async16(Bsrc + kb2 + 2 * b64, dB + 16384);
      async16(Bsrc + kb2 + 3 * b64, dB + 24576);
    }
    __builtin_amdgcn_s_barrier();
    asm volatile("s_waitcnt lgkmcnt(0)" ::: "memory");
    __builtin_amdgcn_s_setprio(1);
#pragma unroll
    for (int i = 0; i < 4; i++)
#pragma unroll
      for (int j = 0; j < 4; j++)
        acc[i][j] = __builtin_amdgcn_mfma_f32_16x16x32_bf16(af[i], bf[j], acc[i][j], 0, 0, 0);
    __builtin_amdgcn_s_setprio(0);

    r = (r == 2) ? 0 : r + 1;
  }

  const int quad = lane >> 4;
  const int coll = lane & 15;
  float bv[4] = {0.f, 0.f, 0.f, 0.f};
  if (bias) {
#pragma unroll
    for (int j = 0; j < 4; j++) bv[j] = bias[n_base + wn + j * 16 + coll];
  }
#pragma unroll
  for (int i = 0; i < 4; i++) {
#pragma unroll
    for (int rr2 = 0; rr2 < 4; rr2++) {
      const size_t row = (size_t)(m_base + wm + i * 16 + quad * 4 + rr2);
#pragma unroll
      for (int j = 0; j < 4; j++) {
        const size_t off = row * (size_t)ldc + (n_base + wn + j * 16 + coll);
        Cout[off] = acc[i][j][rr2] + bv[j];
      }
    }
  }
}

// ---------------------------------------------------------------------------
// Fused joint kernel. One block per 128-row m-panel (grid 512, 512 threads).
// LDS: H-tile 128x512 bf16 (131072 B, 16B-block XOR(row&7) swizzle)
//    + W2 panel double buffer 2 x 16384 B (BK=32, rows = n-tile's 256 cols)
//    = 163840 B (160 KiB, max).
// Phase 1: H = tanh(Pe+Pd+b1) -> LDS (computed once, reused by all 8 n-tiles).
// Phase 2: flattened loop g = nt*16+kt (128 iters): entry {vmcnt(0); barrier}
//   (loads for iter g were issued one full iteration earlier -> ~no stall;
//    FIFO vmcnt semantics make vmcnt(0) always-correct), n-tile stores issued
//   at top of next n-tile's first iter (after its entry wait, before staging).
// Wave-tile 64x64 (8 waves 2Mx4N), acc[4][4], 16 MFMA/iter.
// ---------------------------------------------------------------------------
__device__ __forceinline__ void store_tile(float* __restrict__ out,
    const float* __restrict__ b2, floatx4 (&acc)[4][4],
    int m_base, int nt, int wm, int wn, int lane)
{
  const int quad = lane >> 4;
  const int coll = lane & 15;
  const int ncol0 = nt * 256 + wn + coll;
  float bv[4];
#pragma unroll
  for (int j = 0; j < 4; j++) bv[j] = b2[ncol0 + j * 16];
#pragma unroll
  for (int i = 0; i < 4; i++) {
#pragma unroll
    for (int r = 0; r < 4; r++) {
      const size_t row = (size_t)(m_base + wm + i * 16 + quad * 4 + r);
      float* o = out + row * 2048 + ncol0;
#pragma unroll
      for (int j = 0; j < 4; j++) o[j * 16] = acc[i][j][r] + bv[j];
    }
  }
}

__global__ __launch_bounds__(512, 2)
void joint_fused(const float* __restrict__ Pe, const float* __restrict__ Pd,
                 const float* __restrict__ b1, const short* __restrict__ W2b,
                 const float* __restrict__ b2, float* __restrict__ out)
{
  extern __shared__ char lds[];
  short* Hs = (short*)lds;          // 131072 B
  char*  Wb0 = lds + 131072;        // 2 x 16384 B

  const int tid  = threadIdx.x;
  const int lane = tid & 63;
  const int w    = tid >> 6;
  const int wm   = (w >> 2) << 6;   // 0 / 64
  const int wn   = (w & 3) << 6;    // 0 / 64 / 128 / 192
  const int m_base = blockIdx.x << 7;
  const int b  = m_base >> 14;
  const int t0 = (m_base >> 6) & 255;

  // W2 staging geometry: granule h covers panel rows h*128 + (tid>>2),
  // 16B chunk (tid&3); LDS dst = h*8192 + tid*16 (linear, row stride 64B).
  const short* w2base = W2b + ((size_t)(tid >> 2) * 512) + ((tid & 3) << 3);
  char* const wdst = Wb0 + tid * 16;

  // issue panel (nt=0, kt=0) now — flies during the whole H phase
  async16(w2base,             wdst);
  async16(w2base + 128 * 512, wdst + 8192);

  // ---- Phase 1: H-tile = tanh(Pe + Pd + b1) into LDS (swizzled) ----
  {
    const int hrow = tid >> 2;            // 0..127
    const int cseg = (tid & 3) << 7;      // 0/128/256/384
    const float* pe = Pe + (size_t)((b << 8) + t0 + (hrow >> 6)) * 512 + cseg;
    const float* pd = Pd + (size_t)((b << 6) + (hrow & 63)) * 512 + cseg;
    const float* bb = b1 + cseg;
    short* hrowp = Hs + (size_t)hrow * 512;
    const int sw = hrow & 7;
#pragma unroll 4
    for (int j = 0; j < 16; ++j) {
      const float4 e0 = *(const float4*)(pe + j * 8);
      const float4 e1 = *(const float4*)(pe + j * 8 + 4);
      const float4 d0 = *(const float4*)(pd + j * 8);
      const float4 d1 = *(const float4*)(pd + j * 8 + 4);
      const float4 g0 = *(const float4*)(bb + j * 8);
      const float4 g1 = *(const float4*)(bb + j * 8 + 4);
      float x[8] = {e0.x + d0.x + g0.x, e0.y + d0.y + g0.y,
                    e0.z + d0.z + g0.z, e0.w + d0.w + g0.w,
                    e1.x + d1.x + g1.x, e1.y + d1.y + g1.y,
                    e1.z + d1.z + g1.z, e1.w + d1.w + g1.w};
      short8 o;
#pragma unroll
      for (int q = 0; q < 8; q++) {
        const float e  = __expf(2.0f * x[q]);      // inf-safe tanh
        const float th = 1.0f - 2.0f / (e + 1.0f);
        o[q] = f2bf(th);
      }
      const int blk = (cseg >> 3) + j;             // 16B-block 0..63
      *(short8*)(hrowp + (((blk ^ sw)) << 3)) = o;
    }
  }
  __syncthreads();   // drains lgkm (H writes) + vmcnt (panel 0 staged) + barrier

  // ---- Phase 2: 8 n-tiles x 16 K-steps ----
  const int arow = lane & 15;
  const int q4   = lane >> 4;           // 0..3
  const int s7   = arow & 7;
  const char* HsB = (const char*)lds;
  size_t abase[4];
#pragma unroll
  for (int i = 0; i < 4; i++) abase[i] = (size_t)(wm + i * 16 + arow) * 1024;
  int boff[4];
#pragma unroll
  for (int j = 0; j < 4; j++) boff[j] = (wn + j * 16 + arow) * 64 + q4 * 16;

  floatx4 acc[4][4];
#pragma unroll
  for (int i = 0; i < 4; i++)
#pragma unroll
    for (int j = 0; j < 4; j++) acc[i][j] = (floatx4)0.0f;

#pragma unroll 2
  for (int g = 0; g < 128; ++g) {
    const int kt = g & 15;

    if (g > 0) {
      // loads for iter g were issued during iter g-1 (FIFO vmcnt -> correct)
      asm volatile("s_waitcnt vmcnt(0)" ::: "memory");
      __builtin_amdgcn_s_barrier();
      asm volatile("" ::: "memory");
      if (kt == 0) {
        // previous n-tile's output (stores issue AFTER this iter's entry wait,
        // so they never sit between a staged load and its vmcnt wait)
        store_tile(out, b2, acc, m_base, (g >> 4) - 1, wm, wn, lane);
#pragma unroll
        for (int i = 0; i < 4; i++)
#pragma unroll
          for (int j = 0; j < 4; j++) acc[i][j] = (floatx4)0.0f;
      }
    }

    // stage panel for iter g+1 into the other buffer (read last at iter g-1;
    // all waves are past that read: entry barrier of g)
    if (g + 1 < 128) {
      const int nt1 = (g + 1) >> 4, kt1 = (g + 1) & 15;
      const short* src = w2base + (size_t)(nt1 << 8) * 512 + (kt1 << 5);
      char* dst = Wb0 + (((g + 1) & 1) << 14) + tid * 16;
      async16(src,             dst);
      async16(src + 128 * 512, dst + 8192);
    }
    asm volatile("" ::: "memory");

    const char* wb = Wb0 + ((g & 1) << 14);
    short8 af[4], bf[4];
#pragma unroll
    for (int i = 0; i < 4; i++) {
      const int kb = ((kt << 2) | q4) ^ s7;        // full bitwise XOR, matches write
      af[i] = *(const short8*)(HsB + abase[i] + (kb << 4));
    }
#pragma unroll
    for (int j = 0; j < 4; j++) bf[j] = *(const short8*)(wb + boff[j]);

    __builtin_amdgcn_s_setprio(1);
#pragma unroll
    for (int i = 0; i < 4; i++)
#pragma unroll
      for (int j = 0; j < 4; j++)
        acc[i][j] = __builtin_amdgcn_mfma_f32_16x16x32_bf16(af[i], bf[j], acc[i][j], 0, 0, 0);
    __builtin_amdgcn_s_setprio(0);
  }

  store_tile(out, b2, acc, m_base, 7, wm, wn, lane);
}

// ---------------------------------------------------------------------------
extern "C" void kernel_launch(void* const* d_in, const int* in_sizes, int n_in,
                              void* d_out, int out_size, void* d_ws, size_t ws_size,
                              hipStream_t stream)
{
  const float* enc = (const float*)d_in[0];  // (4,256,640)
  const float* dec = (const float*)d_in[1];  // (4,64,640)
  const float* W1  = (const float*)d_in[2];  // (512,1280)
  const float* b1  = (const float*)d_in[3];  // (512,)
  const float* W2  = (const float*)d_in[4];  // (2048,512)
  const float* b2  = (const float*)d_in[5];  // (2048,)
  float* out = (float*)d_out;                // (4,256,64,2048)

  static bool attr_done = false;
  if (!attr_done) {
    hipFuncSetAttribute((const void*)gemm_pipe,
                        hipFuncAttributeMaxDynamicSharedMemorySize, 3 * BUFB);
    hipFuncSetAttribute((const void*)joint_fused,
                        hipFuncAttributeMaxDynamicSharedMemorySize, 163840);
    attr_done = true;
  }

  size_t off = 0;
  auto carve = [&](size_t bytes) -> void* {
    void* p = (char*)d_ws + off;
    off += (bytes + 255) & ~(size_t)255;
    return p;
  };
  short* encb = (short*)carve(1024 * 640 * 2);
  short* decb = (short*)carve(256 * 640 * 2);
  short* W1b  = (short*)carve(512 * 1280 * 2);
  short* W2b  = (short*)carve(2048 * 512 * 2);
  float* Pe   = (float*)carve(1024 * 512 * 4);
  float* Pd   = (float*)carve(256 * 512 * 4);

  // all casts in one launch: 315392 n8-units = 1232 blocks
  cast_all<<<1232, 256, 0, stream>>>(enc, dec, W1, W2, encb, decb, W1b, W2b);

  // enc_proj: M=1024, N=512, K=640 (W1 cols [0,640))
  gemm_pipe<<<16, 512, 3 * BUFB, stream>>>(encb, 640, W1b, 1280, 0,
                                           Pe, 512, nullptr, 640, 1);
  // dec_proj: M=256, N=512, K=640 (W1 cols [640,1280))
  gemm_pipe<<<4, 512, 3 * BUFB, stream>>>(decb, 640, W1b, 1280, 640,
                                          Pd, 512, nullptr, 640, 1);

  // fused joint: grid = 65536/128 = 512 m-panels
  joint_fused<<<512, 512, 163840, stream>>>(Pe, Pd, b1, W2b, b2, out);
}